// Round 1
// baseline (263.886 us; speedup 1.0000x reference)
//
#include <hip/hip_runtime.h>

#define NROWS 8000
#define DDIM 9
#define NCOL4 (NROWS / 4)      // 2000 float4 per output row
#define ROWS_PER_BLK 50        // 160 row-chunks in grid.y
#define NCHUNK 125             // 8000 rows / 64 rows-per-wave

typedef float f32x4 __attribute__((ext_vector_type(4)));

// ---------------------------------------------------------------------------
// K1: one wave per 64-row chunk. Per row: s = sum_j ((x-c)/a)^2, f = x.w+b.
// Wave-level inclusive scan (shuffles, no barriers) -> local cumsums cs1,cs2;
// lane 63 writes chunk totals. (Unchanged from verified 262.9 µs version.)
// ---------------------------------------------------------------------------
__global__ __launch_bounds__(256)
void anfis_rows(const float* __restrict__ x,
                const float* __restrict__ a1p, const float* __restrict__ c1p,
                const float* __restrict__ a2p, const float* __restrict__ c2p,
                const float* __restrict__ w_fc1, const float* __restrict__ b_fc1,
                const float* __restrict__ w_fc2, const float* __restrict__ b_fc2,
                float* __restrict__ cs1o, float* __restrict__ cs2o,
                float2* __restrict__ f12o,
                float* __restrict__ t1o, float* __restrict__ t2o) {
    const int wid  = (blockIdx.x * 256 + threadIdx.x) >> 6;   // chunk id
    const int lane = threadIdx.x & 63;
    if (wid >= NCHUNK) return;
    const int r = wid * 64 + lane;

    const float inv_a1 = 1.0f / a1p[0];
    const float c1 = c1p[0];
    const float inv_a2 = 1.0f / a2p[0];
    const float c2 = c2p[0];

    float s1 = 0.f, s2 = 0.f, d1 = 0.f, d2 = 0.f;
#pragma unroll
    for (int j = 0; j < DDIM; ++j) {
        float xv = x[r * DDIM + j];
        float u1 = (xv - c1) * inv_a1;
        float u2 = (xv - c2) * inv_a2;
        s1 += u1 * u1;
        s2 += u2 * u2;
        d1 += xv * w_fc1[j];
        d2 += xv * w_fc2[j];
    }
    f12o[r] = make_float2(d1 + b_fc1[0], d2 + b_fc2[0]);

    // inclusive wave scan over 64 lanes
#pragma unroll
    for (int d = 1; d < 64; d <<= 1) {
        float n1 = __shfl_up(s1, d, 64);
        float n2 = __shfl_up(s2, d, 64);
        if (lane >= d) { s1 += n1; s2 += n2; }
    }
    cs1o[r] = s1;
    cs2o[r] = s2;
    if (lane == 63) { t1o[wid] = s1; t2o[wid] = s2; }
}

// ---------------------------------------------------------------------------
// K2: out[i][j] = f1[i]*w1b[j] + f2[i]*w2b[j].
// Prologue (ONE barrier total, vs 14-barrier Hillis scan before):
//   - lanes 0..63 of wave 0: each owns chunk totals {2l, 2l+1}; pair-sum,
//     6-step __shfl_up inclusive scan, write EXCLUSIVE chunk prefixes to LDS.
//   - tid < 50 stages this row-strip's f12 into LDS (coalesced once; the
//     per-row access in the store loop becomes a broadcast ds_read_b64
//     instead of 50 VMEM loads per thread).
// Then w1b/w2b in registers via log-space normalization:
//   a = cs1[j]+P1[chunk], b = cs2[j]+P2[chunk]
//   w1b = 1/(1+exp(a-b)), w2b = 1-w1b
// Invalid threads return after the barrier (no later barriers), so the
// store loop is unpredicated: plain dwordx4 stores (fill kernel sustains
// 6.4 TB/s with plain stores).
// ---------------------------------------------------------------------------
__global__ __launch_bounds__(256)
void anfis_out(const float2* __restrict__ f12,
               const float* __restrict__ cs1, const float* __restrict__ cs2,
               const float* __restrict__ t1, const float* __restrict__ t2,
               float* __restrict__ out) {
    __shared__ float sp1[128];             // exclusive chunk prefixes
    __shared__ float sp2[128];
    __shared__ float2 sf[ROWS_PER_BLK];    // this strip's (f1,f2) rows
    const int tid = threadIdx.x;
    const int i0 = blockIdx.y * ROWS_PER_BLK;

    if (tid < ROWS_PER_BLK) sf[tid] = f12[i0 + tid];

    if (tid < 64) {
        const int l = tid;
        float e10 = 0.f, e11 = 0.f, e20 = 0.f, e21 = 0.f;
        if (2 * l < NCHUNK)     { e10 = t1[2 * l];     e20 = t2[2 * l]; }
        if (2 * l + 1 < NCHUNK) { e11 = t1[2 * l + 1]; e21 = t2[2 * l + 1]; }
        const float p1 = e10 + e11, p2 = e20 + e21;   // pair sums
        float s1 = p1, s2 = p2;
        // inclusive scan of pair sums across the wave
#pragma unroll
        for (int d = 1; d < 64; d <<= 1) {
            float n1 = __shfl_up(s1, d, 64);
            float n2 = __shfl_up(s2, d, 64);
            if (l >= d) { s1 += n1; s2 += n2; }
        }
        const float ex1 = s1 - p1, ex2 = s2 - p2;     // exclusive pair prefix
        sp1[2 * l]     = ex1;        sp2[2 * l]     = ex2;
        sp1[2 * l + 1] = ex1 + e10;  sp2[2 * l + 1] = ex2 + e20;
    }
    __syncthreads();

    const int j4 = blockIdx.x * 256 + tid;   // float4 column index
    if (j4 >= NCOL4) return;                 // no barriers after this point
    const int c = j4 >> 4;                   // (j4*4)/64: chunk of these 4 cols

    f32x4 u, v;
    {
        f32x4 a = ((const f32x4*)cs1)[j4] + sp1[c];
        f32x4 b = ((const f32x4*)cs2)[j4] + sp2[c];
#pragma unroll
        for (int q = 0; q < 4; ++q) {
            float e = expf(a[q] - b[q]);
            float inv = 1.0f / (1.0f + e);
            u[q] = inv;        // w1_bar
            v[q] = e * inv;    // w2_bar
        }
    }

    f32x4* orow = (f32x4*)out + (size_t)i0 * NCOL4 + j4;
#pragma unroll 5
    for (int k = 0; k < ROWS_PER_BLK; ++k) {
        const float2 ab = sf[k];             // LDS broadcast
        *orow = ab.x * u + ab.y * v;
        orow += NCOL4;
    }
}

// ---------------------------------------------------------------------------
extern "C" void kernel_launch(void* const* d_in, const int* in_sizes, int n_in,
                              void* d_out, int out_size, void* d_ws, size_t ws_size,
                              hipStream_t stream) {
    const float* x     = (const float*)d_in[0];
    const float* a1    = (const float*)d_in[1];
    const float* c1    = (const float*)d_in[2];
    const float* a2    = (const float*)d_in[3];
    const float* c2    = (const float*)d_in[4];
    const float* w_fc1 = (const float*)d_in[5];
    const float* b_fc1 = (const float*)d_in[6];
    const float* w_fc2 = (const float*)d_in[7];
    const float* b_fc2 = (const float*)d_in[8];
    float* out = (float*)d_out;

    float* ws   = (float*)d_ws;          // ~130 KB used
    float* cs1  = ws;                    // [8000] local inclusive cumsums
    float* cs2  = ws + 8000;
    float2* f12 = (float2*)(ws + 16000); // [8000] float2
    float* t1   = ws + 32000;            // [125] chunk totals
    float* t2   = ws + 32125;

    anfis_rows<<<(NCHUNK * 64 + 255) / 256, 256, 0, stream>>>(
        x, a1, c1, a2, c2, w_fc1, b_fc1, w_fc2, b_fc2, cs1, cs2, f12, t1, t2);
    anfis_out<<<dim3((NCOL4 + 255) / 256, NROWS / ROWS_PER_BLK), 256, 0, stream>>>(
        f12, cs1, cs2, t1, t2, out);
}